// Round 7
// baseline (1172.372 us; speedup 1.0000x reference)
//
#include <hip/hip_runtime.h>
#include <hip/hip_bf16.h>

#define NUM_E 64
#define KTOP 8
#define CAP 512
#define TT 2048
#define DD 2048
#define HH 1024

#define BK 32
#define LDSK 36  // 72B rows: all b64 access classes at the 4-lane/bank minimum

typedef __attribute__((ext_vector_type(4))) float f4v;
typedef __attribute__((ext_vector_type(8))) short bf16x8;
typedef __attribute__((ext_vector_type(4))) short bf16x4;

static __device__ __forceinline__ short f2bf(float f) {
    __bf16 b = (__bf16)f;
    return __builtin_bit_cast(short, b);
}
static __device__ __forceinline__ int imin(int a, int b) { return a < b ? a : b; }

// Barrier WITHOUT vmcnt drain: LDS writes committed (lgkmcnt(0)); global loads
// in flight stay in flight across the barrier (counted-vmcnt pattern).
static __device__ __forceinline__ void pipe_barrier() {
    asm volatile("s_waitcnt lgkmcnt(0)" ::: "memory");
    __builtin_amdgcn_s_barrier();
}

// ---------------- init: zero counts ----------------
__global__ __launch_bounds__(64) void k_init(int* __restrict__ counts) {
    counts[threadIdx.x] = 0;
}

// ---------------- prep: x f32 -> bf16 (stored in out[] region, free 8MB) ----
__global__ __launch_bounds__(256) void k_prep(const float* __restrict__ x,
                                              ushort* __restrict__ xbf) {
    int idx = blockIdx.x * 256 + threadIdx.x;   // 524288 threads, 8 elems each
    size_t i8 = (size_t)idx * 8;
    f4v v0 = *(const f4v*)(x + i8);
    f4v v1 = *(const f4v*)(x + i8 + 4);
    bf16x8 o = {f2bf(v0[0]), f2bf(v0[1]), f2bf(v0[2]), f2bf(v0[3]),
                f2bf(v1[0]), f2bf(v1[1]), f2bf(v1[2]), f2bf(v1[3])};
    *(bf16x8*)(xbf + i8) = o;
}

// ---------------- zero out[] (after gateup consumed xbf, before down) -------
__global__ __launch_bounds__(256) void k_zero(float* __restrict__ out) {
    int idx = blockIdx.x * 256 + threadIdx.x;   // 1048576 threads, one f4v each
    f4v z = {0.f, 0.f, 0.f, 0.f};
    ((f4v*)out)[idx] = z;
}

// ---------------- router: logits = x @ gate_w (f32, exact) ----------------
#define RTOK 8
__global__ __launch_bounds__(256) void k_router(const float* __restrict__ x,
                                                const float* __restrict__ gw,
                                                float* __restrict__ logits) {
    __shared__ float xs[RTOK][512];
    const int tid = threadIdx.x;
    const int lane = tid & 63, wid = tid >> 6;
    const int t0 = blockIdx.x * RTOK;
    float a0 = 0.f, a1 = 0.f;
    for (int c = 0; c < DD / 512; ++c) {
        __syncthreads();
#pragma unroll
        for (int u = tid * 4; u < RTOK * 512; u += 1024) {
            int r = u >> 9, col = u & 511;
            *(f4v*)&xs[r][col] = *(const f4v*)&x[(size_t)(t0 + r) * DD + c * 512 + col];
        }
        __syncthreads();
        const float* gcol = gw + (size_t)c * 512 * NUM_E + lane;
#pragma unroll 8
        for (int d = 0; d < 512; ++d) {
            float g = gcol[(size_t)d * NUM_E];
            a0 = fmaf(xs[wid * 2 + 0][d], g, a0);
            a1 = fmaf(xs[wid * 2 + 1][d], g, a1);
        }
    }
    logits[(size_t)(t0 + wid * 2 + 0) * NUM_E + lane] = a0;
    logits[(size_t)(t0 + wid * 2 + 1) * NUM_E + lane] = a1;
}

// ---------------- topk + dispatch ----------------
__global__ __launch_bounds__(256) void k_topk(const float* __restrict__ logits,
                                              int* __restrict__ counts,
                                              int* __restrict__ slot_token,
                                              float* __restrict__ slot_wt) {
    int lane = threadIdx.x & 63, wid = threadIdx.x >> 6;
    int t = blockIdx.x * 4 + wid;
    float l = logits[(size_t)t * NUM_E + lane];
    float m = l;
#pragma unroll
    for (int off = 32; off; off >>= 1) m = fmaxf(m, __shfl_xor(m, off));
    float ex = __expf(l - m);
    float s = ex;
#pragma unroll
    for (int off = 32; off; off >>= 1) s += __shfl_xor(s, off);
    float p = ex / s;
#pragma unroll
    for (int k = 0; k < KTOP; ++k) {
        float v = p;
        int i = lane;
#pragma unroll
        for (int off = 32; off; off >>= 1) {
            float v2 = __shfl_xor(v, off);
            int i2 = __shfl_xor(i, off);
            if (v2 > v || (v2 == v && i2 < i)) { v = v2; i = i2; }
        }
        if (lane == i) {
            int pos = atomicAdd(&counts[i], 1);
            if (pos < CAP) {
                int slot = i * CAP + pos;
                slot_token[slot] = t;
                slot_wt[slot] = v;
            }
            p = -1.0f;
        }
    }
}

// ================= gate+up fused GEMM + SwiGLU -> h =================
// BM=256, BN=64, 512 threads (8 waves 4m x 2n; wave 64x32 with BOTH g,u accs).
// Role split: waves 0-3 stage B (wg/wu f32 transpose), waves 4-7 stage A (xbf).
// LDS double-buffer; counted vmcnt (loads live across the lgkm-only barrier).
__global__ __launch_bounds__(512, 2) void k_gateup(
    const ushort* __restrict__ xbf, const float* __restrict__ wg, const float* __restrict__ wu,
    const int* __restrict__ counts, const int* __restrict__ slot_token,
    const float* __restrict__ slot_wt, ushort* __restrict__ hbuf) {
    const int e = blockIdx.z;
    int count = counts[e];
    if (count > CAP) count = CAP;
    const int mrow0 = blockIdx.y * 256;
    if (mrow0 >= count) return;
    const int ncol0 = blockIdx.x * 64;
    const int tid = threadIdx.x;
    const int lane = tid & 63, wid = tid >> 6;
    const int wm = wid >> 1, wn = wid & 1;
    const int lrow = lane & 15, g4 = lane >> 4;
    const bool isA = tid >= 256;

    __shared__ ushort As0[256 * LDSK], As1[256 * LDSK];
    __shared__ ushort Bg0[64 * LDSK], Bg1[64 * LDSK];
    __shared__ ushort Bu0[64 * LDSK], Bu1[64 * LDSK];

    // ---- staging addresses ----
    // A role (tid 256..511): t = tid-256; granule g=t&3 (8 elems), ar=t>>2;
    // rows ar + i*64 (i=0..3), 16B contiguous per row per granule.
    const int at = tid & 255;
    const int ag = at & 3, ar = at >> 2;
    const ushort* aptr[4];
    int arowl[4];
    // B role (tid 0..255): mat = tid>>7; ci=(tid&127)&15 col-group; ki=(tid&127)>>4.
    const int bidx = tid & 127;
    const int bc0 = (bidx & 15) * 4;
    const int bk0 = (bidx >> 4) * 4;
    const float* bptr = ((tid & 128) ? wu : wg) + ((size_t)e * DD + bk0) * HH + ncol0 + bc0;
    ushort* bl0 = (tid & 128) ? Bu0 : Bg0;
    ushort* bl1 = (tid & 128) ? Bu1 : Bg1;
#pragma unroll
    for (int i = 0; i < 4; ++i) {
        int rl = ar + i * 64;
        arowl[i] = rl;
        int rg = imin(mrow0 + rl, count - 1);
        int tok = slot_token[e * CAP + rg];
        aptr[i] = xbf + (size_t)tok * DD + ag * 8;
    }

    // unified staging banks (A: 4x bf16x8 bitcast; B: 4x f4v)
    f4v st0[4], st1[4];
    f4v accg[4][2], accu[4][2];
    const f4v fz = {0.f, 0.f, 0.f, 0.f};
#pragma unroll
    for (int m = 0; m < 4; ++m)
#pragma unroll
        for (int n = 0; n < 2; ++n) { accg[m][n] = fz; accu[m][n] = fz; }
    bf16x8 af[4], bgr[2], bur[2];

#define GUL(ST, KO) { \
    if (isA) { _Pragma("unroll") for (int i_ = 0; i_ < 4; ++i_) \
        ST[i_] = __builtin_bit_cast(f4v, *(const bf16x8*)(aptr[i_] + (KO))); } \
    else { _Pragma("unroll") for (int j_ = 0; j_ < 4; ++j_) \
        ST[j_] = *(const f4v*)(bptr + ((size_t)(KO) + j_) * HH); } }

#define GUW(ST, ASB, BLB) { \
    if (isA) { _Pragma("unroll") for (int i_ = 0; i_ < 4; ++i_) { \
        bf16x8 v_ = __builtin_bit_cast(bf16x8, ST[i_]); \
        union { bf16x8 v8; bf16x4 v4[2]; } u_; u_.v8 = v_; \
        *(bf16x4*)&ASB[arowl[i_] * LDSK + ag * 8] = u_.v4[0]; \
        *(bf16x4*)&ASB[arowl[i_] * LDSK + ag * 8 + 4] = u_.v4[1]; } } \
    else { _Pragma("unroll") for (int i_ = 0; i_ < 4; ++i_) { \
        bf16x4 col_ = {f2bf(ST[0][i_]), f2bf(ST[1][i_]), f2bf(ST[2][i_]), f2bf(ST[3][i_])}; \
        *(bf16x4*)&BLB[(bc0 + i_) * LDSK + bk0] = col_; } } }

#define GUF(AS, BG, BU) { \
    _Pragma("unroll") for (int m_ = 0; m_ < 4; ++m_) { \
        const ushort* pa_ = &AS[(wm * 64 + m_ * 16 + lrow) * LDSK + g4 * 4]; \
        union { bf16x8 v8; bf16x4 v4[2]; } u_; \
        u_.v4[0] = *(const bf16x4*)pa_; u_.v4[1] = *(const bf16x4*)(pa_ + 16); \
        af[m_] = u_.v8; } \
    _Pragma("unroll") for (int n_ = 0; n_ < 2; ++n_) { \
        const int c_ = (wn * 32 + n_ * 16 + lrow) * LDSK + g4 * 4; \
        union { bf16x8 v8; bf16x4 v4[2]; } ug_, uu_; \
        ug_.v4[0] = *(const bf16x4*)&BG[c_]; ug_.v4[1] = *(const bf16x4*)&BG[c_ + 16]; \
        uu_.v4[0] = *(const bf16x4*)&BU[c_]; uu_.v4[1] = *(const bf16x4*)&BU[c_ + 16]; \
        bgr[n_] = ug_.v8; bur[n_] = uu_.v8; } }

#define GUM() { \
    _Pragma("unroll") for (int n_ = 0; n_ < 2; ++n_) \
    _Pragma("unroll") for (int m_ = 0; m_ < 4; ++m_) { \
        accg[m_][n_] = __builtin_amdgcn_mfma_f32_16x16x32_bf16(af[m_], bgr[n_], accg[m_][n_], 0, 0, 0); \
        accu[m_][n_] = __builtin_amdgcn_mfma_f32_16x16x32_bf16(af[m_], bur[n_], accu[m_][n_], 0, 0, 0); } }

    // prologue: bank0<-t0, bank1<-t1; buf0 <- bank0 (counted: t1 stays in flight)
    GUL(st0, 0);
    GUL(st1, BK);
    GUW(st0, As0, bl0);
    pipe_barrier();

    const int NK = DD / BK;  // 64, even
    for (int kt = 0; kt < NK; kt += 2) {
        const int ko2 = imin(kt + 2, NK - 1) * BK;  // clamped tail: dummy load,
        const int ko3 = imin(kt + 3, NK - 1) * BK;  // its LDS write never consumed
        // phase 0: consume buf0 (tile kt); write buf1 (tile kt+1)
        GUL(st0, ko2);                 // issue tile kt+2 first: ~1.5-phase cover
        GUF(As0, Bg0, Bu0);
        GUW(st1, As1, bl1);            // vmcnt(4): waits tile kt+1 loads only
        GUM();
        pipe_barrier();
        // phase 1: consume buf1 (tile kt+1); write buf0 (tile kt+2)
        GUL(st1, ko3);
        GUF(As1, Bg1, Bu1);
        GUW(st0, As0, bl0);
        GUM();
        pipe_barrier();
    }

    // epilogue: h = silu(g)*u * gate-weight, bf16
#pragma unroll
    for (int m = 0; m < 4; ++m) {
#pragma unroll
        for (int r = 0; r < 4; ++r) {
            int row = mrow0 + wm * 64 + m * 16 + g4 * 4 + r;
            if (row < count) {
                float wgt = slot_wt[e * CAP + row];
                size_t base = (size_t)(e * CAP + row) * HH + ncol0 + wn * 32;
#pragma unroll
                for (int n = 0; n < 2; ++n) {
                    float g = accg[m][n][r], uv = accu[m][n][r];
                    float hv = (g / (1.f + __expf(-g))) * uv * wgt;
                    hbuf[base + n * 16 + lrow] = (ushort)f2bf(hv);
                }
            }
        }
    }
}

// ================= down GEMM + scatter-add into out =================
// BM=256, BN=128, 512 threads (8 waves 4m x 2n; wave 64x64, 64 acc).
__global__ __launch_bounds__(512, 2) void k_down(
    const ushort* __restrict__ hbuf, const float* __restrict__ wd,
    const int* __restrict__ counts, const int* __restrict__ slot_token,
    float* __restrict__ out) {
    const int e = blockIdx.z;
    int count = counts[e];
    if (count > CAP) count = CAP;
    const int mrow0 = blockIdx.y * 256;
    if (mrow0 >= count) return;
    const int ncol0 = blockIdx.x * 128;
    const int tid = threadIdx.x;
    const int lane = tid & 63, wid = tid >> 6;
    const int wm = wid >> 1, wn = wid & 1;
    const int lrow = lane & 15, g4 = lane >> 4;
    const bool isA = tid >= 256;

    __shared__ ushort As0[256 * LDSK], As1[256 * LDSK];
    __shared__ ushort Bs0[128 * LDSK], Bs1[128 * LDSK];

    const int at = tid & 255;
    const int ag = at & 3, ar = at >> 2;
    const ushort* aptr[4];
    int arowl[4];
#pragma unroll
    for (int i = 0; i < 4; ++i) {
        int rl = ar + i * 64;
        arowl[i] = rl;
        int rg = imin(mrow0 + rl, count - 1);
        aptr[i] = hbuf + (size_t)(e * CAP + rg) * HH + ag * 8;
    }
    // B: tid 0..255: ci = tid&31 (32 col-groups x 4 = 128 cols), ki = tid>>5 (8 x 4k)
    const int bc0 = (tid & 31) * 4;
    const int bk0 = ((tid >> 5) & 7) * 4;
    const float* bptr = wd + ((size_t)e * HH + bk0) * DD + ncol0 + bc0;

    f4v st0[4], st1[4];
    f4v acc[4][4];
    const f4v fz = {0.f, 0.f, 0.f, 0.f};
#pragma unroll
    for (int m = 0; m < 4; ++m)
#pragma unroll
        for (int n = 0; n < 4; ++n) acc[m][n] = fz;
    bf16x8 af[4], bfr[4];

#define DNL(ST, KO) { \
    if (isA) { _Pragma("unroll") for (int i_ = 0; i_ < 4; ++i_) \
        ST[i_] = __builtin_bit_cast(f4v, *(const bf16x8*)(aptr[i_] + (KO))); } \
    else { _Pragma("unroll") for (int j_ = 0; j_ < 4; ++j_) \
        ST[j_] = *(const f4v*)(bptr + ((size_t)(KO) + j_) * DD); } }

#define DNW(ST, ASB, BSB) { \
    if (isA) { _Pragma("unroll") for (int i_ = 0; i_ < 4; ++i_) { \
        bf16x8 v_ = __builtin_bit_cast(bf16x8, ST[i_]); \
        union { bf16x8 v8; bf16x4 v4[2]; } u_; u_.v8 = v_; \
        *(bf16x4*)&ASB[arowl[i_] * LDSK + ag * 8] = u_.v4[0]; \
        *(bf16x4*)&ASB[arowl[i_] * LDSK + ag * 8 + 4] = u_.v4[1]; } } \
    else { _Pragma("unroll") for (int i_ = 0; i_ < 4; ++i_) { \
        bf16x4 col_ = {f2bf(ST[0][i_]), f2bf(ST[1][i_]), f2bf(ST[2][i_]), f2bf(ST[3][i_])}; \
        *(bf16x4*)&BSB[(bc0 + i_) * LDSK + bk0] = col_; } } }

#define DNF(AS, BS) { \
    _Pragma("unroll") for (int m_ = 0; m_ < 4; ++m_) { \
        const ushort* pa_ = &AS[(wm * 64 + m_ * 16 + lrow) * LDSK + g4 * 4]; \
        union { bf16x8 v8; bf16x4 v4[2]; } u_; \
        u_.v4[0] = *(const bf16x4*)pa_; u_.v4[1] = *(const bf16x4*)(pa_ + 16); \
        af[m_] = u_.v8; } \
    _Pragma("unroll") for (int n_ = 0; n_ < 4; ++n_) { \
        const int c_ = (wn * 64 + n_ * 16 + lrow) * LDSK + g4 * 4; \
        union { bf16x8 v8; bf16x4 v4[2]; } ub_; \
        ub_.v4[0] = *(const bf16x4*)&BS[c_]; ub_.v4[1] = *(const bf16x4*)&BS[c_ + 16]; \
        bfr[n_] = ub_.v8; } }

#define DNM() { \
    _Pragma("unroll") for (int n_ = 0; n_ < 4; ++n_) \
    _Pragma("unroll") for (int m_ = 0; m_ < 4; ++m_) \
        acc[m_][n_] = __builtin_amdgcn_mfma_f32_16x16x32_bf16(af[m_], bfr[n_], acc[m_][n_], 0, 0, 0); }

    DNL(st0, 0);
    DNL(st1, BK);
    DNW(st0, As0, Bs0);
    pipe_barrier();

    const int NK = HH / BK;  // 32, even
    for (int kt = 0; kt < NK; kt += 2) {
        const int ko2 = imin(kt + 2, NK - 1) * BK;
        const int ko3 = imin(kt + 3, NK - 1) * BK;
        DNL(st0, ko2);
        DNF(As0, Bs0);
        DNW(st1, As1, Bs1);
        DNM();
        pipe_barrier();
        DNL(st1, ko3);
        DNF(As1, Bs1);
        DNW(st0, As0, Bs0);
        DNM();
        pipe_barrier();
    }

#pragma unroll
    for (int m = 0; m < 4; ++m) {
#pragma unroll
        for (int r = 0; r < 4; ++r) {
            int row = mrow0 + wm * 64 + m * 16 + g4 * 4 + r;
            if (row < count) {
                int tok = slot_token[e * CAP + row];
                float* obase = out + (size_t)tok * DD + ncol0 + wn * 64;
#pragma unroll
                for (int n = 0; n < 4; ++n) atomicAdd(obase + n * 16 + lrow, acc[m][n][r]);
            }
        }
    }
}

extern "C" void kernel_launch(void* const* d_in, const int* in_sizes, int n_in,
                              void* d_out, int out_size, void* d_ws, size_t ws_size,
                              hipStream_t stream) {
    const float* x = (const float*)d_in[0];       // [1,2048,2048]
    const float* gw = (const float*)d_in[1];      // [2048,64]
    const float* wg = (const float*)d_in[2];      // [64,2048,1024]
    const float* wu = (const float*)d_in[3];      // [64,2048,1024]
    const float* wd = (const float*)d_in[4];      // [64,1024,2048]
    float* out = (float*)d_out;                   // [T*D] then logits [T*E]
    float* logits = out + (size_t)TT * DD;

    char* ws = (char*)d_ws;
    int* counts = (int*)ws;                                      // 256 B
    int* slot_token = (int*)(ws + 1024);                         // 128 KB
    float* slot_wt = (float*)(ws + 1024 + NUM_E * CAP * 4);      // 128 KB
    ushort* hbuf = (ushort*)(ws + 1024 + 2 * NUM_E * CAP * 4);   // 64 MB bf16 [E*CAP][H]
    // xbf (8 MB bf16 copy of x) lives in the out[] region: written by k_prep,
    // consumed by k_gateup, erased by k_zero before k_down's atomics.
    ushort* xbf = (ushort*)out;

    k_init<<<1, 64, 0, stream>>>(counts);
    k_prep<<<(TT * DD / 8) / 256, 256, 0, stream>>>(x, xbf);
    k_router<<<TT / RTOK, 256, 0, stream>>>(x, gw, logits);
    k_topk<<<TT / 4, 256, 0, stream>>>(logits, counts, slot_token, slot_wt);
    k_gateup<<<dim3(HH / 64, CAP / 256, NUM_E), 512, 0, stream>>>(xbf, wg, wu, counts, slot_token, slot_wt, hbuf);
    k_zero<<<(TT * DD / 4) / 256, 256, 0, stream>>>(out);
    k_down<<<dim3(DD / 128, CAP / 256, NUM_E), 512, 0, stream>>>(hbuf, wd, counts, slot_token, out);
}

// Round 8
// 816.619 us; speedup vs baseline: 1.4356x; 1.4356x over previous
//
#include <hip/hip_runtime.h>
#include <hip/hip_bf16.h>

#define NUM_E 64
#define KTOP 8
#define CAP 512
#define TT 2048
#define DD 2048
#define HH 1024

#define BK 32
#define LDSK 36  // 72B rows: all b64 access classes at the 4-lane/bank minimum

typedef __attribute__((ext_vector_type(4))) float f4v;
typedef __attribute__((ext_vector_type(8))) short bf16x8;
typedef __attribute__((ext_vector_type(4))) short bf16x4;

static __device__ __forceinline__ short f2bf(float f) {
    __bf16 b = (__bf16)f;
    return __builtin_bit_cast(short, b);
}
static __device__ __forceinline__ int imin(int a, int b) { return a < b ? a : b; }

// Barrier WITHOUT vmcnt drain: LDS writes committed (lgkmcnt(0)); global loads
// in flight stay in flight across the barrier.
static __device__ __forceinline__ void pipe_barrier() {
    asm volatile("s_waitcnt lgkmcnt(0)" ::: "memory");
    __builtin_amdgcn_s_barrier();
}

// ---------------- init: zero counts ----------------
__global__ __launch_bounds__(64) void k_init(int* __restrict__ counts) {
    counts[threadIdx.x] = 0;
}

// ---------------- prep: x f32 -> bf16 (stored in out[] region, free 8MB) ----
__global__ __launch_bounds__(256) void k_prep(const float* __restrict__ x,
                                              ushort* __restrict__ xbf) {
    int idx = blockIdx.x * 256 + threadIdx.x;
    size_t i8 = (size_t)idx * 8;
    f4v v0 = *(const f4v*)(x + i8);
    f4v v1 = *(const f4v*)(x + i8 + 4);
    bf16x8 o = {f2bf(v0[0]), f2bf(v0[1]), f2bf(v0[2]), f2bf(v0[3]),
                f2bf(v1[0]), f2bf(v1[1]), f2bf(v1[2]), f2bf(v1[3])};
    *(bf16x8*)(xbf + i8) = o;
}

// ---------------- zero out[] (after gateup consumed xbf, before down) -------
__global__ __launch_bounds__(256) void k_zero(float* __restrict__ out) {
    int idx = blockIdx.x * 256 + threadIdx.x;
    f4v z = {0.f, 0.f, 0.f, 0.f};
    ((f4v*)out)[idx] = z;
}

// ---------------- router: logits = x @ gate_w (f32, exact) ----------------
#define RTOK 8
__global__ __launch_bounds__(256) void k_router(const float* __restrict__ x,
                                                const float* __restrict__ gw,
                                                float* __restrict__ logits) {
    __shared__ float xs[RTOK][512];
    const int tid = threadIdx.x;
    const int lane = tid & 63, wid = tid >> 6;
    const int t0 = blockIdx.x * RTOK;
    float a0 = 0.f, a1 = 0.f;
    for (int c = 0; c < DD / 512; ++c) {
        __syncthreads();
#pragma unroll
        for (int u = tid * 4; u < RTOK * 512; u += 1024) {
            int r = u >> 9, col = u & 511;
            *(f4v*)&xs[r][col] = *(const f4v*)&x[(size_t)(t0 + r) * DD + c * 512 + col];
        }
        __syncthreads();
        const float* gcol = gw + (size_t)c * 512 * NUM_E + lane;
#pragma unroll 8
        for (int d = 0; d < 512; ++d) {
            float g = gcol[(size_t)d * NUM_E];
            a0 = fmaf(xs[wid * 2 + 0][d], g, a0);
            a1 = fmaf(xs[wid * 2 + 1][d], g, a1);
        }
    }
    logits[(size_t)(t0 + wid * 2 + 0) * NUM_E + lane] = a0;
    logits[(size_t)(t0 + wid * 2 + 1) * NUM_E + lane] = a1;
}

// ---------------- topk + dispatch ----------------
__global__ __launch_bounds__(256) void k_topk(const float* __restrict__ logits,
                                              int* __restrict__ counts,
                                              int* __restrict__ slot_token,
                                              float* __restrict__ slot_wt) {
    int lane = threadIdx.x & 63, wid = threadIdx.x >> 6;
    int t = blockIdx.x * 4 + wid;
    float l = logits[(size_t)t * NUM_E + lane];
    float m = l;
#pragma unroll
    for (int off = 32; off; off >>= 1) m = fmaxf(m, __shfl_xor(m, off));
    float ex = __expf(l - m);
    float s = ex;
#pragma unroll
    for (int off = 32; off; off >>= 1) s += __shfl_xor(s, off);
    float p = ex / s;
#pragma unroll
    for (int k = 0; k < KTOP; ++k) {
        float v = p;
        int i = lane;
#pragma unroll
        for (int off = 32; off; off >>= 1) {
            float v2 = __shfl_xor(v, off);
            int i2 = __shfl_xor(i, off);
            if (v2 > v || (v2 == v && i2 < i)) { v = v2; i = i2; }
        }
        if (lane == i) {
            int pos = atomicAdd(&counts[i], 1);
            if (pos < CAP) {
                int slot = i * CAP + pos;
                slot_token[slot] = t;
                slot_wt[slot] = v;
            }
            p = -1.0f;
        }
    }
}

// ================= gate+up fused GEMM + SwiGLU -> h =================
// 128x64 tile, 4 waves (2x2), wave 64x32 dual g+u acc. LDS double-buffer.
// Phase order: FRAG -> WRITE(st=t+1; outstanding loads are old => cheap vmcnt)
//   -> LOAD(st<-t+2; covered by MFMA+barrier+next FRAG) -> MFMA -> lgkm barrier.
// Single staging bank. A pre-converted to bf16 (xbf).
__global__ __launch_bounds__(256, 3) void k_gateup(
    const ushort* __restrict__ xbf, const float* __restrict__ wg, const float* __restrict__ wu,
    const int* __restrict__ counts, const int* __restrict__ slot_token,
    const float* __restrict__ slot_wt, ushort* __restrict__ hbuf) {
    const int e = blockIdx.z;
    int count = counts[e];
    if (count > CAP) count = CAP;
    const int mrow0 = blockIdx.y * 128;
    if (mrow0 >= count) return;
    const int ncol0 = blockIdx.x * 64;
    const int tid = threadIdx.x;
    const int lane = tid & 63, wid = tid >> 6;
    const int wm = wid >> 1, wn = wid & 1;
    const int lrow = lane & 15, g4 = lane >> 4;

    __shared__ ushort As0[128 * LDSK], As1[128 * LDSK];
    __shared__ ushort Bg0[64 * LDSK], Bg1[64 * LDSK];
    __shared__ ushort Bu0[64 * LDSK], Bu1[64 * LDSK];

    // A staging: unit = 16B granule. gran=tid&3 (k-offset gran*8), rowbase=tid>>2,
    // rows rowbase + i*64 (i=0,1). Pure bf16 copy, no cvt.
    const int agran = tid & 3;
    const ushort* aptr[2];
    int arowl[2];
#pragma unroll
    for (int i = 0; i < 2; ++i) {
        int rl = (tid >> 2) + i * 64;
        arowl[i] = rl;
        int rg = imin(mrow0 + rl, count - 1);
        int tok = slot_token[e * CAP + rg];
        aptr[i] = xbf + (size_t)tok * DD + agran * 8;
    }
    // B staging: tid&128 selects wg/wu; 4 h-cols x 4 k per unit (transpose in regs).
    const int bidx = tid & 127;
    const int bc0 = (bidx & 15) * 4;
    const int bk0 = (bidx >> 4) * 4;
    const float* bptr = ((tid & 128) ? wu : wg) + ((size_t)e * DD + bk0) * HH + ncol0 + bc0;
    ushort* bl0 = (tid & 128) ? Bu0 : Bg0;
    ushort* bl1 = (tid & 128) ? Bu1 : Bg1;

    f4v stB[4];        // 4 strided f4v (weights)
    bf16x8 stA[2];     // 2 row-granules
    f4v accg[4][2], accu[4][2];
    const f4v fz = {0.f, 0.f, 0.f, 0.f};
#pragma unroll
    for (int m = 0; m < 4; ++m)
#pragma unroll
        for (int n = 0; n < 2; ++n) { accg[m][n] = fz; accu[m][n] = fz; }
    bf16x8 af[4], bgr[2], bur[2];

#define GUL(KO) { \
    _Pragma("unroll") for (int i_ = 0; i_ < 2; ++i_) stA[i_] = *(const bf16x8*)(aptr[i_] + (KO)); \
    _Pragma("unroll") for (int j_ = 0; j_ < 4; ++j_) stB[j_] = *(const f4v*)(bptr + ((size_t)(KO) + j_) * HH); }

#define GUW(ASB, BLB) { \
    _Pragma("unroll") for (int i_ = 0; i_ < 2; ++i_) { \
        union { bf16x8 v8; bf16x4 v4[2]; } u_; u_.v8 = stA[i_]; \
        *(bf16x4*)&ASB[arowl[i_] * LDSK + agran * 8] = u_.v4[0]; \
        *(bf16x4*)&ASB[arowl[i_] * LDSK + agran * 8 + 4] = u_.v4[1]; } \
    _Pragma("unroll") for (int i_ = 0; i_ < 4; ++i_) { \
        bf16x4 col_ = {f2bf(stB[0][i_]), f2bf(stB[1][i_]), f2bf(stB[2][i_]), f2bf(stB[3][i_])}; \
        *(bf16x4*)&BLB[(bc0 + i_) * LDSK + bk0] = col_; } }

#define GUF(AS, BG, BU) { \
    _Pragma("unroll") for (int m_ = 0; m_ < 4; ++m_) { \
        const ushort* pa_ = &AS[(wm * 64 + m_ * 16 + lrow) * LDSK + g4 * 4]; \
        union { bf16x8 v8; bf16x4 v4[2]; } u_; \
        u_.v4[0] = *(const bf16x4*)pa_; u_.v4[1] = *(const bf16x4*)(pa_ + 16); \
        af[m_] = u_.v8; } \
    _Pragma("unroll") for (int n_ = 0; n_ < 2; ++n_) { \
        const int c_ = (wn * 32 + n_ * 16 + lrow) * LDSK + g4 * 4; \
        union { bf16x8 v8; bf16x4 v4[2]; } ug_, uu_; \
        ug_.v4[0] = *(const bf16x4*)&BG[c_]; ug_.v4[1] = *(const bf16x4*)&BG[c_ + 16]; \
        uu_.v4[0] = *(const bf16x4*)&BU[c_]; uu_.v4[1] = *(const bf16x4*)&BU[c_ + 16]; \
        bgr[n_] = ug_.v8; bur[n_] = uu_.v8; } }

#define GUM() { \
    _Pragma("unroll") for (int n_ = 0; n_ < 2; ++n_) \
    _Pragma("unroll") for (int m_ = 0; m_ < 4; ++m_) { \
        accg[m_][n_] = __builtin_amdgcn_mfma_f32_16x16x32_bf16(af[m_], bgr[n_], accg[m_][n_], 0, 0, 0); \
        accu[m_][n_] = __builtin_amdgcn_mfma_f32_16x16x32_bf16(af[m_], bur[n_], accu[m_][n_], 0, 0, 0); } }

    // prologue: st<-t0; buf0<-st; st<-t1; barrier
    GUL(0);
    GUW(As0, bl0);
    GUL(BK);
    pipe_barrier();

    const int NK = DD / BK;  // 64, even
    for (int kt = 0; kt < NK; kt += 2) {
        const int ko2 = imin(kt + 2, NK - 1) * BK;  // clamped tail: dummy reload,
        const int ko3 = imin(kt + 3, NK - 1) * BK;  // its LDS write never consumed
        // phase 0: consume buf0 (tile kt)
        GUF(As0, Bg0, Bu0);
        GUW(As1, bl1);     // st = t(kt+1), loads issued a full phase ago
        GUL(ko2);          // st <- t(kt+2); covered by MFMA+barrier+next FRAG
        GUM();
        pipe_barrier();
        // phase 1: consume buf1 (tile kt+1)
        GUF(As1, Bg1, Bu1);
        GUW(As0, bl0);     // st = t(kt+2)
        GUL(ko3);          // st <- t(kt+3)
        GUM();
        pipe_barrier();
    }

    // epilogue: h = silu(g)*u * gate-weight, bf16
#pragma unroll
    for (int m = 0; m < 4; ++m) {
#pragma unroll
        for (int r = 0; r < 4; ++r) {
            int row = mrow0 + wm * 64 + m * 16 + g4 * 4 + r;
            if (row < count) {
                float wgt = slot_wt[e * CAP + row];
                size_t base = (size_t)(e * CAP + row) * HH + ncol0 + wn * 32;
#pragma unroll
                for (int n = 0; n < 2; ++n) {
                    float g = accg[m][n][r], uv = accu[m][n][r];
                    float hv = (g / (1.f + __expf(-g))) * uv * wgt;
                    hbuf[base + n * 16 + lrow] = (ushort)f2bf(hv);
                }
            }
        }
    }
}

// ================= down GEMM + scatter-add into out =================
// 128x128 tile, 4 waves (2x2), wave 64x64. Same reordered pipeline.
__global__ __launch_bounds__(256, 3) void k_down(
    const ushort* __restrict__ hbuf, const float* __restrict__ wd,
    const int* __restrict__ counts, const int* __restrict__ slot_token,
    float* __restrict__ out) {
    const int e = blockIdx.z;
    int count = counts[e];
    if (count > CAP) count = CAP;
    const int mrow0 = blockIdx.y * 128;
    if (mrow0 >= count) return;
    const int ncol0 = blockIdx.x * 128;
    const int tid = threadIdx.x;
    const int lane = tid & 63, wid = tid >> 6;
    const int wm = wid >> 1, wn = wid & 1;
    const int lrow = lane & 15, g4 = lane >> 4;

    __shared__ ushort As0[128 * LDSK], As1[128 * LDSK];
    __shared__ ushort Bs0[128 * LDSK], Bs1[128 * LDSK];

    const int agran = tid & 3;
    const ushort* aptr[2];
    int arowl[2];
#pragma unroll
    for (int i = 0; i < 2; ++i) {
        int rl = (tid >> 2) + i * 64;
        arowl[i] = rl;
        int rg = imin(mrow0 + rl, count - 1);
        aptr[i] = hbuf + (size_t)(e * CAP + rg) * HH + agran * 8;
    }
    const int bc0 = (tid & 31) * 4;
    const int bk0 = ((tid >> 5) & 7) * 4;
    const float* bptr = wd + ((size_t)e * HH + bk0) * DD + ncol0 + bc0;

    f4v stB[4];
    bf16x8 stA[2];
    f4v acc[4][4];
    const f4v fz = {0.f, 0.f, 0.f, 0.f};
#pragma unroll
    for (int m = 0; m < 4; ++m)
#pragma unroll
        for (int n = 0; n < 4; ++n) acc[m][n] = fz;
    bf16x8 af[4], bfr[4];

#define DNL(KO) { \
    _Pragma("unroll") for (int i_ = 0; i_ < 2; ++i_) stA[i_] = *(const bf16x8*)(aptr[i_] + (KO)); \
    _Pragma("unroll") for (int j_ = 0; j_ < 4; ++j_) stB[j_] = *(const f4v*)(bptr + ((size_t)(KO) + j_) * DD); }

#define DNW(ASB, BSB) { \
    _Pragma("unroll") for (int i_ = 0; i_ < 2; ++i_) { \
        union { bf16x8 v8; bf16x4 v4[2]; } u_; u_.v8 = stA[i_]; \
        *(bf16x4*)&ASB[arowl[i_] * LDSK + agran * 8] = u_.v4[0]; \
        *(bf16x4*)&ASB[arowl[i_] * LDSK + agran * 8 + 4] = u_.v4[1]; } \
    _Pragma("unroll") for (int i_ = 0; i_ < 4; ++i_) { \
        bf16x4 col_ = {f2bf(stB[0][i_]), f2bf(stB[1][i_]), f2bf(stB[2][i_]), f2bf(stB[3][i_])}; \
        *(bf16x4*)&BSB[(bc0 + i_) * LDSK + bk0] = col_; } }

#define DNF(AS, BS) { \
    _Pragma("unroll") for (int m_ = 0; m_ < 4; ++m_) { \
        const ushort* pa_ = &AS[(wm * 64 + m_ * 16 + lrow) * LDSK + g4 * 4]; \
        union { bf16x8 v8; bf16x4 v4[2]; } u_; \
        u_.v4[0] = *(const bf16x4*)pa_; u_.v4[1] = *(const bf16x4*)(pa_ + 16); \
        af[m_] = u_.v8; } \
    _Pragma("unroll") for (int n_ = 0; n_ < 4; ++n_) { \
        const int c_ = (wn * 64 + n_ * 16 + lrow) * LDSK + g4 * 4; \
        union { bf16x8 v8; bf16x4 v4[2]; } ub_; \
        ub_.v4[0] = *(const bf16x4*)&BS[c_]; ub_.v4[1] = *(const bf16x4*)&BS[c_ + 16]; \
        bfr[n_] = ub_.v8; } }

#define DNM() { \
    _Pragma("unroll") for (int n_ = 0; n_ < 4; ++n_) \
    _Pragma("unroll") for (int m_ = 0; m_ < 4; ++m_) \
        acc[m_][n_] = __builtin_amdgcn_mfma_f32_16x16x32_bf16(af[m_], bfr[n_], acc[m_][n_], 0, 0, 0); }

    DNL(0);
    DNW(As0, Bs0);
    DNL(BK);
    pipe_barrier();

    const int NK = HH / BK;  // 32, even
    for (int kt = 0; kt < NK; kt += 2) {
        const int ko2 = imin(kt + 2, NK - 1) * BK;
        const int ko3 = imin(kt + 3, NK - 1) * BK;
        DNF(As0, Bs0);
        DNW(As1, Bs1);
        DNL(ko2);
        DNM();
        pipe_barrier();
        DNF(As1, Bs1);
        DNW(As0, Bs0);
        DNL(ko3);
        DNM();
        pipe_barrier();
    }

#pragma unroll
    for (int m = 0; m < 4; ++m) {
#pragma unroll
        for (int r = 0; r < 4; ++r) {
            int row = mrow0 + wm * 64 + m * 16 + g4 * 4 + r;
            if (row < count) {
                int tok = slot_token[e * CAP + row];
                float* obase = out + (size_t)tok * DD + ncol0 + wn * 64;
#pragma unroll
                for (int n = 0; n < 4; ++n) atomicAdd(obase + n * 16 + lrow, acc[m][n][r]);
            }
        }
    }
}

extern "C" void kernel_launch(void* const* d_in, const int* in_sizes, int n_in,
                              void* d_out, int out_size, void* d_ws, size_t ws_size,
                              hipStream_t stream) {
    const float* x = (const float*)d_in[0];       // [1,2048,2048]
    const float* gw = (const float*)d_in[1];      // [2048,64]
    const float* wg = (const float*)d_in[2];      // [64,2048,1024]
    const float* wu = (const float*)d_in[3];      // [64,2048,1024]
    const float* wd = (const float*)d_in[4];      // [64,1024,2048]
    float* out = (float*)d_out;                   // [T*D] then logits [T*E]
    float* logits = out + (size_t)TT * DD;

    char* ws = (char*)d_ws;
    int* counts = (int*)ws;                                      // 256 B
    int* slot_token = (int*)(ws + 1024);                         // 128 KB
    float* slot_wt = (float*)(ws + 1024 + NUM_E * CAP * 4);      // 128 KB
    ushort* hbuf = (ushort*)(ws + 1024 + 2 * NUM_E * CAP * 4);   // 64 MB bf16 [E*CAP][H]
    // xbf (8 MB bf16 copy of x) lives in out[]: written by k_prep, read by
    // k_gateup, erased by k_zero before k_down's atomics. logits at +16MB safe.
    ushort* xbf = (ushort*)out;

    k_init<<<1, 64, 0, stream>>>(counts);
    k_prep<<<(TT * DD / 8) / 256, 256, 0, stream>>>(x, xbf);
    k_router<<<TT / RTOK, 256, 0, stream>>>(x, gw, logits);
    k_topk<<<TT / 4, 256, 0, stream>>>(logits, counts, slot_token, slot_wt);
    k_gateup<<<dim3(HH / 64, CAP / 128, NUM_E), 256, 0, stream>>>(xbf, wg, wu, counts, slot_token, slot_wt, hbuf);
    k_zero<<<(TT * DD / 4) / 256, 256, 0, stream>>>(out);
    k_down<<<dim3(DD / 128, CAP / 128, NUM_E), 256, 0, stream>>>(hbuf, wd, counts, slot_token, out);
}